// Round 2
// baseline (159.608 us; speedup 1.0000x reference)
//
#include <hip/hip_runtime.h>
#include <math.h>

#define NB 32    // batch
#define NS 128   // steps
#define NI 256   // in_dim
#define NC 128   // num capsules
#define ND 64    // dim capsule

#define L4 9.210340371976184f  // ln(10000)

// ---------------------------------------------------------------------------
// k_prep: one launch computing
//   blocks [0,1024):        M[b,s,d] = sum_i u*W ; U[b,s] = sum_i u
//   blocks [1024,5120):     pe2n[n][s][d]   (n-major trig table)
//   blocks [5120,9216):     pe2sT[s][d][n]  (transposed trig table)
//   blocks [9216,9248):     PE1[n][d]
// ---------------------------------------------------------------------------
__global__ __launch_bounds__(256) void k_prep(const float* __restrict__ u,
                                              const float* __restrict__ W,
                                              float* __restrict__ M,
                                              float* __restrict__ U,
                                              float* __restrict__ PE1,
                                              float* __restrict__ pe2n,
                                              float* __restrict__ pe2sT) {
    int blk = blockIdx.x;
    int t = threadIdx.x;
    if (blk < 1024) {
        int row = blk * 4 + (t >> 6);   // b*NS + s
        int d = t & 63;
        const float* ur = u + row * NI;
        float acc = 0.f, rs = 0.f;
#pragma unroll 4
        for (int i = 0; i < NI; ++i) {
            float v = ur[i];
            acc = fmaf(v, W[i * ND + d], acc);
            rs += v;
        }
        M[row * ND + d] = acc;
        if (d == 0) U[row] = rs;
    } else if (blk < 1024 + 4096) {
        int idx = (blk - 1024) * 256 + t;          // 1M elems
        int n = idx >> 13, s = (idx >> 6) & 127, d = idx & 63;
        int k2 = (n << 5) + (d >> 1);
        float g = __expf(-L4 * (float)k2 * (1.f / 4096.f));
        float sv, cv;
        __sincosf((float)s * g, &sv, &cv);
        pe2n[idx] = (d & 1) ? cv : sv;
    } else if (blk < 1024 + 8192) {
        int idx = (blk - 1024 - 4096) * 256 + t;   // 1M elems
        int s = idx >> 13, d = (idx >> 7) & 63, n = idx & 127;
        int k2 = (n << 5) + (d >> 1);
        float g = __expf(-L4 * (float)k2 * (1.f / 4096.f));
        float sv, cv;
        __sincosf((float)s * g, &sv, &cv);
        pe2sT[idx] = (d & 1) ? cv : sv;
    } else {
        int idx = (blk - 1024 - 8192) * 256 + t;   // 8192 elems
        int n = idx >> 6, d = idx & 63;
        float ang = (float)n * __expf(-L4 * (float)(d >> 1) * (1.f / 32.f));
        float sv, cv;
        __sincosf(ang, &sv, &cv);
        PE1[idx] = (d & 1) ? cv : sv;
    }
}

// ---------------------------------------------------------------------------
// k_out: out[b,n,:] = squash( sum_s c*(M + pe2n) + pe1*(sum_s c*U) )
// Also emits PU[b,n] = sum_d out*pe1 (needed by k_logits).
// Tile: 2 b x 4 n per block; 8 groups of 32 lanes, one (b,n) per group,
// lane j owns d-pair (2j,2j+1). grid = 16*32 = 512 blocks.
// ---------------------------------------------------------------------------
__global__ __launch_bounds__(256) void k_out(const float* __restrict__ M,
                                             const float* __restrict__ U,
                                             const float* __restrict__ PE1,
                                             const float* __restrict__ pe2n,
                                             const float* __restrict__ c,
                                             const float* __restrict__ mask,
                                             float* __restrict__ og,
                                             float* __restrict__ PU,
                                             int first) {
    int blk = blockIdx.x;              // btile*32 + ntile  (ntile%8 -> XCD locality)
    int btile = blk >> 5, ntile = blk & 31;
    int b0 = btile * 2, n0 = ntile * 4;
    int t = threadIdx.x;

    __shared__ float ct[2][NS][4];     // c[b][s][n-tile]
    __shared__ float Us[2][NS];
    __shared__ float pe1t[4][ND];

    {
        int bh = t >> 7, sh = t & 127;
        if (first) {
            float v = mask[(b0 + bh) * NS + sh] * (1.f / 128.f);
            ct[bh][sh][0] = v; ct[bh][sh][1] = v; ct[bh][sh][2] = v; ct[bh][sh][3] = v;
        } else {
            const float4 cv4 = *(const float4*)(c + ((b0 + bh) * NS + sh) * NC + n0);
            ct[bh][sh][0] = cv4.x; ct[bh][sh][1] = cv4.y;
            ct[bh][sh][2] = cv4.z; ct[bh][sh][3] = cv4.w;
        }
        Us[bh][sh] = U[(b0 + bh) * NS + sh];
        pe1t[t >> 6][t & 63] = PE1[(n0 + (t >> 6)) * ND + (t & 63)];
    }
    __syncthreads();

    int g = t >> 5, j = t & 31;
    int bh = g >> 2, nh = g & 3;
    int b = b0 + bh, n = n0 + nh;
    int d0 = j * 2;

    const float* Mp = M + (b * NS) * ND + d0;
    const float* Pp = pe2n + (n * NS) * ND + d0;
    float ax = 0.f, ay = 0.f;
#pragma unroll 4
    for (int s = 0; s < NS; ++s) {
        float cs = ct[bh][s][nh];
        float2 m2 = *(const float2*)(Mp + s * ND);
        float2 p2 = *(const float2*)(Pp + s * ND);
        ax = fmaf(cs, m2.x + p2.x, ax);
        ay = fmaf(cs, m2.y + p2.y, ay);
    }

    // CU = sum_s c*U  (shfl reduce within the 32-lane group)
    float cu = 0.f;
#pragma unroll
    for (int k = 0; k < 4; ++k) {
        int s = j + 32 * k;
        cu += ct[bh][s][nh] * Us[bh][s];
    }
#pragma unroll
    for (int o = 16; o > 0; o >>= 1) cu += __shfl_xor(cu, o);

    float p1x = pe1t[nh][d0], p1y = pe1t[nh][d0 + 1];
    float ox = fmaf(cu, p1x, ax), oy = fmaf(cu, p1y, ay);

    float ss = ox * ox + oy * oy;
#pragma unroll
    for (int o = 16; o > 0; o >>= 1) ss += __shfl_xor(ss, o);
    float scale = ss / (1.f + ss) * rsqrtf(ss + 1e-7f);
    ox *= scale; oy *= scale;
    *(float2*)(og + (b * NC + n) * ND + d0) = make_float2(ox, oy);

    float pu = ox * p1x + oy * p1y;
#pragma unroll
    for (int o = 16; o > 0; o >>= 1) pu += __shfl_xor(pu, o);
    if (j == 0) PU[b * NC + n] = pu;
}

// ---------------------------------------------------------------------------
// k_logits: ln[b,s,n] = sum_d out*(M[b,s,d] + pe2sT[s,d,n]) + PU[b,n]*U[b,s]
// then c[b][s][n] = softmax_n(ln) * mask[b,s].
// Block = (b, 4 s), 256 thr = 128 n-lanes x 2 d-halves. grid = 32*32 = 1024.
// ---------------------------------------------------------------------------
__global__ __launch_bounds__(256) void k_logits(const float* __restrict__ M,
                                                const float* __restrict__ U,
                                                const float* __restrict__ PU,
                                                const float* __restrict__ pe2sT,
                                                const float* __restrict__ og,
                                                const float* __restrict__ mask,
                                                float* __restrict__ c) {
    int blk = blockIdx.x;              // b*32 + stile
    int b = blk >> 5, s0 = (blk & 31) * 4;
    int t = threadIdx.x;

    __shared__ float ol[NC][ND + 1];   // out[b][n][d], stride 65 -> 2-way banks
    __shared__ float Ms[4][ND];
    __shared__ float PUs[NC];
    __shared__ float red[4][NC][2];
    __shared__ float wred[4];
    __shared__ float Usb[4], mkv[4];

    // stage out[b] (32 KB) via float4 global loads
    const float4* ob4 = (const float4*)(og + b * NC * ND);
#pragma unroll
    for (int k = 0; k < 8; ++k) {
        int f = k * 256 + t;           // float4 index in [0,2048)
        float4 v = ob4[f];
        int n = f >> 4, d = (f & 15) * 4;
        ol[n][d] = v.x; ol[n][d + 1] = v.y; ol[n][d + 2] = v.z; ol[n][d + 3] = v.w;
    }
    {
        int sh = t >> 6, d = t & 63;
        Ms[sh][d] = M[(b * NS + s0 + sh) * ND + d];
    }
    if (t < NC) PUs[t] = PU[b * NC + t];
    if (t < 4) { Usb[t] = U[b * NS + s0 + t]; mkv[t] = mask[b * NS + s0 + t]; }
    __syncthreads();

    int n = t & 127, h = t >> 7;
    int dbase = h * 32;
    float acc0 = 0.f, acc1 = 0.f, acc2 = 0.f, acc3 = 0.f;
    const float* P0 = pe2sT + ((s0 + 0) * ND + dbase) * NC + n;
    const float* P1 = pe2sT + ((s0 + 1) * ND + dbase) * NC + n;
    const float* P2 = pe2sT + ((s0 + 2) * ND + dbase) * NC + n;
    const float* P3 = pe2sT + ((s0 + 3) * ND + dbase) * NC + n;
#pragma unroll 4
    for (int dd = 0; dd < 32; ++dd) {
        int d = dbase + dd;
        float ov = ol[n][d];
        acc0 = fmaf(ov, Ms[0][d] + P0[dd * NC], acc0);
        acc1 = fmaf(ov, Ms[1][d] + P1[dd * NC], acc1);
        acc2 = fmaf(ov, Ms[2][d] + P2[dd * NC], acc2);
        acc3 = fmaf(ov, Ms[3][d] + P3[dd * NC], acc3);
    }
    red[0][n][h] = acc0; red[1][n][h] = acc1;
    red[2][n][h] = acc2; red[3][n][h] = acc3;
    __syncthreads();

    // fused softmax over n (per s), all 256 threads participate in barriers
    for (int sh = 0; sh < 4; ++sh) {
        float ln = -1e30f;
        if (t < NC) ln = red[sh][n][0] + red[sh][n][1] + PUs[n] * Usb[sh];
        float mx = ln;
#pragma unroll
        for (int o = 32; o > 0; o >>= 1) mx = fmaxf(mx, __shfl_xor(mx, o));
        if ((t & 63) == 0) wred[t >> 6] = mx;
        __syncthreads();
        mx = fmaxf(fmaxf(wred[0], wred[1]), fmaxf(wred[2], wred[3]));
        __syncthreads();
        float e = (t < NC) ? __expf(ln - mx) : 0.f;
        float sm = e;
#pragma unroll
        for (int o = 32; o > 0; o >>= 1) sm += __shfl_xor(sm, o);
        if ((t & 63) == 0) wred[t >> 6] = sm;
        __syncthreads();
        float tot = wred[0] + wred[1] + wred[2] + wred[3];
        if (t < NC) c[(b * NS + s0 + sh) * NC + n] = e / tot * mkv[sh];
        __syncthreads();
    }
}

// ---------------------------------------------------------------------------
extern "C" void kernel_launch(void* const* d_in, const int* in_sizes, int n_in,
                              void* d_out, int out_size, void* d_ws, size_t ws_size,
                              hipStream_t stream) {
    const float* u    = (const float*)d_in[0];  // (32,128,256)
    const float* mask = (const float*)d_in[1];  // (32,128)
    const float* W    = (const float*)d_in[2];  // (1,256,64)
    float* out = (float*)d_out;                 // (32,128,64)

    float* ws    = (float*)d_ws;
    float* M     = ws;                          // 262144
    float* U     = M + NB * NS * ND;            // 4096
    float* PE1   = U + NB * NS;                 // 8192
    float* pe2n  = PE1 + NC * ND;               // 1048576
    float* pe2sT = pe2n + NC * NS * ND;         // 1048576
    float* c     = pe2sT + NS * ND * NC;        // 524288
    float* PU    = c + NB * NS * NC;            // 4096

    k_prep<<<9248, 256, 0, stream>>>(u, W, M, U, PE1, pe2n, pe2sT);

    // iter 0 (uniform c = mask/128)
    k_out<<<512, 256, 0, stream>>>(M, U, PE1, pe2n, c, mask, out, PU, 1);
    k_logits<<<1024, 256, 0, stream>>>(M, U, PU, pe2sT, out, mask, c);
    // iter 1
    k_out<<<512, 256, 0, stream>>>(M, U, PE1, pe2n, c, mask, out, PU, 0);
    k_logits<<<1024, 256, 0, stream>>>(M, U, PU, pe2sT, out, mask, c);
    // iter 2 (final) -> d_out
    k_out<<<512, 256, 0, stream>>>(M, U, PE1, pe2n, c, mask, out, PU, 0);
}